// Round 1
// 138.436 us; speedup vs baseline: 1.0037x; 1.0037x over previous
//
#include <hip/hip_runtime.h>
#include <hip/hip_bf16.h>

#define BATCH 4096
#define DIM 64
#define KN 50
#define NL 3

typedef __attribute__((ext_vector_type(8))) short short8;   // 8 bf16 = 4 VGPRs
typedef __attribute__((ext_vector_type(4))) float f32x4;

static __device__ __forceinline__ unsigned short f2bf(float f) {
    union { __hip_bfloat16 h; unsigned short u; } cv;
    cv.h = __float2bfloat16(f);
    return cv.u;
}

// ---------------------------------------------------------------------------
// Fused gather + 3-layer MLP.
// Grid 256 x 1024 threads: 16 rows/block, 1 row/wave (16 waves/CU during the
// gather phase -- same TLP as the old standalone gather kernel).
// Gather: 16-lane group g handles k = 4t+g with float4 (dwordx4) row loads:
// 50 dword loads/row -> 13 dwordx4 loads/row. Cross-group combine via 2-step
// shfl_xor butterfly. X0/NM1/NM2 never touch HBM: transposed into LDS and
// consumed by the MLP phase (waves 0..3, 4 rows/wave, same FMA scheme as the
// previous mlp_kernel: 1 conflict-free W ds_read + 1 broadcast x-quad per i).
// ---------------------------------------------------------------------------
__global__ __launch_bounds__(1024) void fused_kernel(
    const int* __restrict__ user_ids,
    const int* __restrict__ item_ids,
    const int* __restrict__ nbrs,
    const float* __restrict__ mask,
    const float* __restrict__ user_table,
    const float* __restrict__ item_table,
    const float* __restrict__ Ws,
    const float* __restrict__ bs,
    __hip_bfloat16* __restrict__ Uout,
    __hip_bfloat16* __restrict__ Iout)
{
    __shared__ float Wlds[NL * 64 * 65];   // 48.75 KB, +1 padded rows
    __shared__ float blds[NL * 64];
    __shared__ float xT2[64][16];          // [dim][row-in-block] layer input
    __shared__ float nm1T2[64][16];
    __shared__ float nm2T2[64][16];

    const int tid = threadIdx.x;

    // ---- stage W (float4 global loads, conflict-free LDS writes) ----
    #pragma unroll
    for (int p = 0; p < 3; ++p) {
        const int f4 = tid + p * 1024;         // 3072 float4 total
        const int idx = f4 << 2;
        const int l = idx >> 12;
        const int rem = idx & 4095;
        const int j = rem >> 6;
        const int i = rem & 63;
        const float4 wv = *reinterpret_cast<const float4*>(&Ws[idx]);
        *reinterpret_cast<float4*>(&Wlds[l * (64 * 65) + j * 65 + i]) = wv;
    }
    if (tid < NL * 64) blds[tid] = bs[tid];

    const int wave = tid >> 6;
    const int lane = tid & 63;
    const int g = lane >> 4;                  // k-phase (k mod 4)
    const int m = lane & 15;                  // dim-quad index
    const int b = __builtin_amdgcn_readfirstlane((blockIdx.x << 4) + wave);

    // item embedding -> bf16 (scalar row id, float4 read, 8B packed store)
    const int it = item_ids[b];
    const float4 iv = *reinterpret_cast<const float4*>(&item_table[it * DIM + (m << 2)]);

    // user embedding (row-uniform; every group loads the same quad, L1-hit)
    const int u = user_ids[b];
    const float4 x = *reinterpret_cast<const float4*>(&user_table[u * DIM + (m << 2)]);

    const int* __restrict__ nrow = nbrs + b * KN;
    const float* __restrict__ mrow = mask + b * KN;

    float4 a1 = {0.f, 0.f, 0.f, 0.f};
    float4 a2 = {0.f, 0.f, 0.f, 0.f};
    float4 a3 = {0.f, 0.f, 0.f, 0.f};

    #pragma unroll
    for (int t = 0; t < 12; ++t) {
        const int k = (t << 2) + g;
        const int nk = nrow[k];               // group-uniform dword
        const float wk = mrow[k];             // group-uniform dword
        const float4 v = *reinterpret_cast<const float4*>(&user_table[nk * DIM + (m << 2)]);
        const float w2 = wk * wk;
        const float w3 = w2 * wk;
        a1.x = fmaf(wk, v.x, a1.x); a1.y = fmaf(wk, v.y, a1.y);
        a1.z = fmaf(wk, v.z, a1.z); a1.w = fmaf(wk, v.w, a1.w);
        a2.x = fmaf(w2, v.x, a2.x); a2.y = fmaf(w2, v.y, a2.y);
        a2.z = fmaf(w2, v.z, a2.z); a2.w = fmaf(w2, v.w, a2.w);
        a3.x = fmaf(w3, v.x, a3.x); a3.y = fmaf(w3, v.y, a3.y);
        a3.z = fmaf(w3, v.z, a3.z); a3.w = fmaf(w3, v.w, a3.w);
    }
    if (g < 2) {                              // tail: k = 48, 49
        const int k = 48 + g;
        const int nk = nrow[k];
        const float wk = mrow[k];
        const float4 v = *reinterpret_cast<const float4*>(&user_table[nk * DIM + (m << 2)]);
        const float w2 = wk * wk;
        const float w3 = w2 * wk;
        a1.x = fmaf(wk, v.x, a1.x); a1.y = fmaf(wk, v.y, a1.y);
        a1.z = fmaf(wk, v.z, a1.z); a1.w = fmaf(wk, v.w, a1.w);
        a2.x = fmaf(w2, v.x, a2.x); a2.y = fmaf(w2, v.y, a2.y);
        a2.z = fmaf(w2, v.z, a2.z); a2.w = fmaf(w2, v.w, a2.w);
        a3.x = fmaf(w3, v.x, a3.x); a3.y = fmaf(w3, v.y, a3.y);
        a3.z = fmaf(w3, v.z, a3.z); a3.w = fmaf(w3, v.w, a3.w);
    }

    // butterfly across the 4 k-phase groups (lane bits 4,5)
    a1.x += __shfl_xor(a1.x, 16); a1.y += __shfl_xor(a1.y, 16);
    a1.z += __shfl_xor(a1.z, 16); a1.w += __shfl_xor(a1.w, 16);
    a2.x += __shfl_xor(a2.x, 16); a2.y += __shfl_xor(a2.y, 16);
    a2.z += __shfl_xor(a2.z, 16); a2.w += __shfl_xor(a2.w, 16);
    a3.x += __shfl_xor(a3.x, 16); a3.y += __shfl_xor(a3.y, 16);
    a3.z += __shfl_xor(a3.z, 16); a3.w += __shfl_xor(a3.w, 16);
    a1.x += __shfl_xor(a1.x, 32); a1.y += __shfl_xor(a1.y, 32);
    a1.z += __shfl_xor(a1.z, 32); a1.w += __shfl_xor(a1.w, 32);
    a2.x += __shfl_xor(a2.x, 32); a2.y += __shfl_xor(a2.y, 32);
    a2.z += __shfl_xor(a2.z, 32); a2.w += __shfl_xor(a2.w, 32);
    a3.x += __shfl_xor(a3.x, 32); a3.y += __shfl_xor(a3.y, 32);
    a3.z += __shfl_xor(a3.z, 32); a3.w += __shfl_xor(a3.w, 32);

    if (lane < 16) {
        const float inv = 1.0f / (float)KN;
        const int i0 = lane << 2;
        // transpose into [dim][row] layout (12 scalar ds_writes, once/row)
        xT2[i0 + 0][wave] = x.x + a1.x * inv;
        xT2[i0 + 1][wave] = x.y + a1.y * inv;
        xT2[i0 + 2][wave] = x.z + a1.z * inv;
        xT2[i0 + 3][wave] = x.w + a1.w * inv;
        nm1T2[i0 + 0][wave] = a2.x * inv;
        nm1T2[i0 + 1][wave] = a2.y * inv;
        nm1T2[i0 + 2][wave] = a2.z * inv;
        nm1T2[i0 + 3][wave] = a2.w * inv;
        nm2T2[i0 + 0][wave] = a3.x * inv;
        nm2T2[i0 + 1][wave] = a3.y * inv;
        nm2T2[i0 + 2][wave] = a3.z * inv;
        nm2T2[i0 + 3][wave] = a3.w * inv;
        ushort4 ip;
        ip.x = f2bf(iv.x); ip.y = f2bf(iv.y); ip.z = f2bf(iv.z); ip.w = f2bf(iv.w);
        *reinterpret_cast<ushort4*>(&Iout[b * DIM + i0]) = ip;
    }

    __syncthreads();

    // ---- MLP phase: waves 0..3, 4 rows/wave ----
    if (wave >= 4) return;
    const int w4 = wave << 2;                 // rows w4..w4+3 of this block

    float x0, x1, x2, x3;
    #pragma unroll
    for (int l = 0; l < NL; ++l) {
        if (l > 0)
            *reinterpret_cast<float4*>(&xT2[lane][w4]) = make_float4(x0, x1, x2, x3);
        float y0 = blds[(l << 6) + lane], y1 = y0, y2 = y0, y3 = y0;
        const float* wrow = &Wlds[l * (64 * 65) + lane * 65];
        #pragma unroll
        for (int i = 0; i < 64; ++i) {
            const float w = wrow[i];          // conflict-free b32 (stride 65)
            const float4 xv = *reinterpret_cast<const float4*>(&xT2[i][w4]);  // broadcast
            y0 = fmaf(w, xv.x, y0);
            y1 = fmaf(w, xv.y, y1);
            y2 = fmaf(w, xv.z, y2);
            y3 = fmaf(w, xv.w, y3);
        }
        if (l == 0) {
            const float4 nv = *reinterpret_cast<const float4*>(&nm1T2[lane][w4]);
            x0 = fmaxf(y0, 0.f) + nv.x; x1 = fmaxf(y1, 0.f) + nv.y;
            x2 = fmaxf(y2, 0.f) + nv.z; x3 = fmaxf(y3, 0.f) + nv.w;
        } else if (l == 1) {
            const float4 nv = *reinterpret_cast<const float4*>(&nm2T2[lane][w4]);
            x0 = fmaxf(y0, 0.f) + nv.x; x1 = fmaxf(y1, 0.f) + nv.y;
            x2 = fmaxf(y2, 0.f) + nv.z; x3 = fmaxf(y3, 0.f) + nv.w;
        } else {
            x0 = fmaxf(y0, 0.f); x1 = fmaxf(y1, 0.f);
            x2 = fmaxf(y2, 0.f); x3 = fmaxf(y3, 0.f);
        }
    }
    const int rb = (blockIdx.x << 4) + w4;
    Uout[(rb + 0) * DIM + lane] = __float2bfloat16(x0);
    Uout[(rb + 1) * DIM + lane] = __float2bfloat16(x1);
    Uout[(rb + 2) * DIM + lane] = __float2bfloat16(x2);
    Uout[(rb + 3) * DIM + lane] = __float2bfloat16(x3);
}

// ---------------------------------------------------------------------------
// scores = U [4096,64] @ I^T via mfma_f32_16x16x32_bf16, zero LDS.
// Operand-swapped (A=V,B=U). Write-bound (64 MiB C) -> nontemporal stores
// keep the single-use C stream from write-allocating through the 4 MiB/XCD L2.
// ---------------------------------------------------------------------------
__global__ __launch_bounds__(256) void scores_kernel(
    const __hip_bfloat16* __restrict__ U,
    const __hip_bfloat16* __restrict__ V,
    float* __restrict__ C)
{
    const int tid = threadIdx.x;
    const int wave = tid >> 6;
    const int lane = tid & 63;
    const int quad = lane >> 4;
    const int l16 = lane & 15;

    const int row0 = (blockIdx.y << 6) + (wave << 4);
    const int colG = blockIdx.x << 8;

    const short* Us = (const short*)U;
    const short* Vs = (const short*)V;

    const short* up = Us + (row0 + l16) * DIM + quad * 8;
    const short8 u0 = *(const short8*)(up);
    const short8 u1 = *(const short8*)(up + 32);

    #pragma unroll 4
    for (int ct = 0; ct < 16; ++ct) {
        const int col0 = colG + (ct << 4);
        const short* vp = Vs + (col0 + l16) * DIM + quad * 8;
        const short8 v0 = *(const short8*)(vp);
        const short8 v1 = *(const short8*)(vp + 32);
        f32x4 acc = {0.f, 0.f, 0.f, 0.f};
        acc = __builtin_amdgcn_mfma_f32_16x16x32_bf16(v0, u0, acc, 0, 0, 0);
        acc = __builtin_amdgcn_mfma_f32_16x16x32_bf16(v1, u1, acc, 0, 0, 0);
        float* cp = C + (size_t)(row0 + l16) * BATCH + col0 + (quad << 2);
        __builtin_nontemporal_store(acc, (f32x4*)cp);
    }
}

extern "C" void kernel_launch(void* const* d_in, const int* in_sizes, int n_in,
                              void* d_out, int out_size, void* d_ws, size_t ws_size,
                              hipStream_t stream)
{
    const int* user_ids   = (const int*)d_in[0];
    const int* item_ids   = (const int*)d_in[1];
    const int* nbrs       = (const int*)d_in[2];
    const float* mask     = (const float*)d_in[3];
    const float* utable   = (const float*)d_in[4];
    const float* itable   = (const float*)d_in[5];
    const float* Ws       = (const float*)d_in[6];
    const float* bs       = (const float*)d_in[7];
    float* out = (float*)d_out;

    __hip_bfloat16* Ubf = (__hip_bfloat16*)d_ws;          // [4096][64] bf16
    __hip_bfloat16* Ibf = Ubf + BATCH * DIM;              // [4096][64] bf16

    fused_kernel<<<BATCH / 16, 1024, 0, stream>>>(user_ids, item_ids, nbrs, mask,
                                                  utable, itable, Ws, bs, Ubf, Ibf);
    scores_kernel<<<dim3(16, 64), 256, 0, stream>>>(Ubf, Ibf, out);
}